// Round 10
// baseline (78.334 us; speedup 1.0000x reference)
//
#include <hip/hip_runtime.h>
#include <stdint.h>

#define CIN 3
#define WW 512
#define HW (512 * 512)
#define COUT 64
#define KF 48          // 3*4*4
#define HO 128
#define WO 128
#define LDA 52

#define NTAB 512
#define YMIN (-12.0f)
#define YMAX (12.0f)
#define INVH ((float)NTAB / (YMAX - YMIN))
// ws layout (floats):
//   [0]=sigma, [1]=a=INVH/sigma, [2..65]=o_c (bias in table units)
//   [128 .. 128+2*NTAB)      = table (f0, df) pairs  (1024 floats)
//   [1152 .. 1152+1536)      = W' f16 fragments (32x32x16 MFMA B-order)
#define WS_TAB_OFF 128
#define WS_WP (WS_TAB_OFF + 2 * NTAB)
#define WS_FLOATS (WS_WP + 1536)

typedef __attribute__((ext_vector_type(16))) float f32x16;
typedef __attribute__((ext_vector_type(4))) float f32x4v;
typedef __fp16 half2t __attribute__((ext_vector_type(2)));
typedef __fp16 half8 __attribute__((ext_vector_type(8)));

union H8 { half8 h; half2t h2[4]; __fp16 e[8]; uint32_t u[4]; float f[4]; };

// f32x8 -> f16x8 via packed RTZ converts (1 inst per pair)
__device__ __forceinline__ half8 cvt8_rtz(float4 a, float4 b) {
  H8 r;
  r.h2[0] = __builtin_amdgcn_cvt_pkrtz(a.x, a.y);
  r.h2[1] = __builtin_amdgcn_cvt_pkrtz(a.z, a.w);
  r.h2[2] = __builtin_amdgcn_cvt_pkrtz(b.x, b.y);
  r.h2[3] = __builtin_amdgcn_cvt_pkrtz(b.z, b.w);
  return r.h;
}

__device__ __forceinline__ float vq_eval(float y, const float* __restrict__ c) {
  float d[8], m;
#pragma unroll
  for (int k = 0; k < 8; ++k) { float t = y - c[k]; d[k] = t * t; }
  m = fminf(fminf(fminf(d[0], d[1]), fminf(d[2], d[3])),
            fminf(fminf(d[4], d[5]), fminf(d[6], d[7])));
  float num = 0.f, den = 0.f;
#pragma unroll
  for (int k = 0; k < 8; ++k) {
    float e = __expf(m - d[k]);
    den += e;
    num = fmaf(c[k], e, num);
  }
  return num / den;
}

// ---------------------------------------------------------------------------
// Kernel 1 (2 blocks): block 1 = VQ table + per-channel offsets.
// block 0 = sigma (G=W^T W, 4 squarings, 6 matvecs, Rayleigh), then writes
// W' = W*(INVH/sigma) converted to f16 in 32x32x16 MFMA B-fragment order:
// slot = (ct*3+kk)*64 + lane; ch = ct*32+(lane&31), kbase = kk*16+(lane>>5)*8.
// ---------------------------------------------------------------------------
__global__ __launch_bounds__(256) void prep_sigma(
    const float* __restrict__ w, const float* __restrict__ bias,
    const float* __restrict__ centers, float* __restrict__ ws, int build_tab) {
  const int t = threadIdx.x;

  if (blockIdx.x == 1) {
    float c[8];
#pragma unroll
    for (int k = 0; k < 8; ++k) c[k] = centers[k];
    const float h = (YMAX - YMIN) / (float)NTAB;
#pragma unroll 1
    for (int k = t; k < NTAB; k += 256) {
      float y0 = YMIN + (float)k * h;
      float f0 = vq_eval(y0, c);
      float f1 = vq_eval(y0 + h, c);
      ws[WS_TAB_OFF + 2 * k]     = f0;
      ws[WS_TAB_OFF + 2 * k + 1] = f1 - f0;
    }
    if (t < COUT) ws[2 + t] = (bias[t] - YMIN) * INVH;
    return;
  }

  __shared__ float sW[COUT * KF];
  __shared__ float sG[KF * LDA];
  __shared__ float sA[KF * LDA];
  __shared__ float sB[KF * LDA];
  __shared__ float sv[64];
  __shared__ float sp[256];
  __shared__ float s_a;

  {
    const float4* w4 = (const float4*)w;
    float4* s4 = (float4*)sW;
#pragma unroll
    for (int q = 0; q < 3; ++q) s4[q * 256 + t] = w4[q * 256 + t];
  }
  __syncthreads();

  const int ti = t >> 4, tj = t & 15;
  const int i0 = 3 * ti, j0 = 3 * tj;
  {
    float acc[3][3] = {{0.f}};
#pragma unroll 4
    for (int m = 0; m < COUT; ++m) {
      const float* wr = sW + m * KF;
      float a0 = wr[i0], a1 = wr[i0 + 1], a2 = wr[i0 + 2];
      float b0 = wr[j0], b1 = wr[j0 + 1], b2 = wr[j0 + 2];
      acc[0][0] = fmaf(a0, b0, acc[0][0]);
      acc[0][1] = fmaf(a0, b1, acc[0][1]);
      acc[0][2] = fmaf(a0, b2, acc[0][2]);
      acc[1][0] = fmaf(a1, b0, acc[1][0]);
      acc[1][1] = fmaf(a1, b1, acc[1][1]);
      acc[1][2] = fmaf(a1, b2, acc[1][2]);
      acc[2][0] = fmaf(a2, b0, acc[2][0]);
      acc[2][1] = fmaf(a2, b1, acc[2][1]);
      acc[2][2] = fmaf(a2, b2, acc[2][2]);
    }
#pragma unroll
    for (int ii = 0; ii < 3; ++ii)
#pragma unroll
      for (int jj = 0; jj < 3; ++jj) {
        sG[(i0 + ii) * LDA + j0 + jj] = acc[ii][jj];
        sA[(i0 + ii) * LDA + j0 + jj] = acc[ii][jj];
      }
  }
  __syncthreads();

#pragma unroll 1
  for (int s = 0; s < 4; ++s) {
    const float* src = (s & 1) ? sB : sA;
    float* dst = (s & 1) ? sA : sB;
    float acc[3][3] = {{0.f}};
#pragma unroll
    for (int q = 0; q < 12; ++q) {
      float4 ar0 = *(const float4*)(src + (i0 + 0) * LDA + 4 * q);
      float4 ar1 = *(const float4*)(src + (i0 + 1) * LDA + 4 * q);
      float4 ar2 = *(const float4*)(src + (i0 + 2) * LDA + 4 * q);
      float4 br0 = *(const float4*)(src + (j0 + 0) * LDA + 4 * q);
      float4 br1 = *(const float4*)(src + (j0 + 1) * LDA + 4 * q);
      float4 br2 = *(const float4*)(src + (j0 + 2) * LDA + 4 * q);
#define DOT4(A, B, C) \
      C = fmaf(A.x, B.x, C); C = fmaf(A.y, B.y, C); \
      C = fmaf(A.z, B.z, C); C = fmaf(A.w, B.w, C);
      DOT4(ar0, br0, acc[0][0]); DOT4(ar0, br1, acc[0][1]); DOT4(ar0, br2, acc[0][2]);
      DOT4(ar1, br0, acc[1][0]); DOT4(ar1, br1, acc[1][1]); DOT4(ar1, br2, acc[1][2]);
      DOT4(ar2, br0, acc[2][0]); DOT4(ar2, br1, acc[2][1]); DOT4(ar2, br2, acc[2][2]);
#undef DOT4
    }
    __syncthreads();
#pragma unroll
    for (int ii = 0; ii < 3; ++ii)
#pragma unroll
      for (int jj = 0; jj < 3; ++jj)
        dst[(i0 + ii) * LDA + j0 + jj] = acc[ii][jj];
    __syncthreads();
  }
  const float* M = sA;   // G^16

  if (t < 64) sv[t] = (t < KF) ? 1.0f : 0.f;
  __syncthreads();

#pragma unroll 1
  for (int it = 0; it < 6; ++it) {
    float partial = 0.f;
    if (t < 192) {
      const int row = t >> 2, seg = t & 3;
      const float* mr = M + row * LDA + seg * 12;
      const float4* v4 = (const float4*)sv;
#pragma unroll
      for (int q = 0; q < 3; ++q) {
        float4 m4 = *(const float4*)(mr + 4 * q);
        float4 vv = v4[seg * 3 + q];
        partial = fmaf(m4.x, vv.x, partial);
        partial = fmaf(m4.y, vv.y, partial);
        partial = fmaf(m4.z, vv.z, partial);
        partial = fmaf(m4.w, vv.w, partial);
      }
    }
    sp[t] = partial;
    __syncthreads();
    if (t < 64) {
      float nv = 0.f;
      if (t < KF) nv = (sp[4 * t] + sp[4 * t + 1]) + (sp[4 * t + 2] + sp[4 * t + 3]);
      float ss = nv * nv;
#pragma unroll
      for (int m = 32; m >= 1; m >>= 1) ss += __shfl_xor(ss, m, 64);
      sv[t] = (t < KF) ? nv * rsqrtf(ss) : 0.f;
    }
    __syncthreads();
  }

  {
    float partial = 0.f;
    if (t < 192) {
      const int row = t >> 2, seg = t & 3;
      const float* mr = sG + row * LDA + seg * 12;
      const float4* v4 = (const float4*)sv;
#pragma unroll
      for (int q = 0; q < 3; ++q) {
        float4 m4 = *(const float4*)(mr + 4 * q);
        float4 vv = v4[seg * 3 + q];
        partial = fmaf(m4.x, vv.x, partial);
        partial = fmaf(m4.y, vv.y, partial);
        partial = fmaf(m4.z, vv.z, partial);
        partial = fmaf(m4.w, vv.w, partial);
      }
    }
    sp[t] = partial;
    __syncthreads();
    if (t < 64) {
      float nv = 0.f;
      if (t < KF) nv = (sp[4 * t] + sp[4 * t + 1]) + (sp[4 * t + 2] + sp[4 * t + 3]);
      float vt = sv[t];
      float num = nv * vt;
      float den = vt * vt;
#pragma unroll
      for (int m = 32; m >= 1; m >>= 1) {
        num += __shfl_xor(num, m, 64);
        den += __shfl_xor(den, m, 64);
      }
      if (t == 0) {
        float sg = sqrtf(num / den);
        ws[0] = sg;
        ws[1] = INVH / sg;
        s_a = INVH / sg;
      }
    }
  }
  __syncthreads();

  // ---- W' f16 fragments (B-operand order): 384 slots, strided over 256 thr
  if (build_tab) {
    const float a = s_a;
#pragma unroll 1
    for (int sl = t; sl < 384; sl += 256) {
      const int grp = sl >> 6;       // ct*3 + kk
      const int ct = grp / 3;
      const int kk = grp % 3;
      const int l  = sl & 63;
      const int ch = ct * 32 + (l & 31);
      const int kbase = kk * 16 + (l >> 5) * 8;
      const float* src = w + ch * KF + kbase;
      float4 fa = *(const float4*)(src);
      float4 fb = *(const float4*)(src + 4);
      H8 r;
      r.e[0] = (__fp16)(fa.x * a);
      r.e[1] = (__fp16)(fa.y * a);
      r.e[2] = (__fp16)(fa.z * a);
      r.e[3] = (__fp16)(fa.w * a);
      r.e[4] = (__fp16)(fb.x * a);
      r.e[5] = (__fp16)(fb.y * a);
      r.e[6] = (__fp16)(fb.z * a);
      r.e[7] = (__fp16)(fb.w * a);
      *(float4*)(ws + WS_WP + sl * 4) =
          make_float4(r.f[0], r.f[1], r.f[2], r.f[3]);
    }
  }
}

// ---------------------------------------------------------------------------
// Kernel 2: f16 32x32x16 MFMA conv + table-VQ, operand-swapped, 2-tile loop.
// Block = 4 waves = (2 ct x 2 pt), covers one full output row (b,i): 128 pos
// x 64 ch over NT=2 tile iterations.  Grid = 2048 = 8 blocks/CU (100% occ).
// Staging = 1 float4/thread (4 KB table); W frags held in regs across tiles.
// ---------------------------------------------------------------------------
__global__ __launch_bounds__(256) void conv_vq_mfma4(
    const float* __restrict__ x, const float* __restrict__ params,
    float* __restrict__ out) {
  __shared__ float stab[2 * NTAB];   // 4 KB (f0, df)
  __shared__ float sso[COUT];
  const int t = threadIdx.x;
  {
    const float4* src = (const float4*)(params + WS_TAB_OFF);
    ((float4*)stab)[t] = src[t];     // 2*NTAB*4B / 16B == 256 == blockDim
    if (t < COUT) sso[t] = params[2 + t];
  }
  __syncthreads();

  const int lane = t & 63;
  const int wv   = t >> 6;
  const int ct   = wv & 1;                  // channel tile (32 ch)
  const int pt   = wv >> 1;                 // position subtile (32 pos)
  const int h    = lane >> 5;               // k-half
  const int pl   = lane & 31;               // A-row = position-in-tile

  const int n0   = blockIdx.x * 128;        // one full (b,i) row
  const int b    = n0 >> 14;
  const int i    = (n0 & 16383) >> 7;

  // ---- B (W') fragments: loaded once, held across tiles (L2-hot) ----
  const half8* wp = (const half8*)(params + WS_WP);
  half8 Wf[3];
#pragma unroll
  for (int kk = 0; kk < 3; ++kk) Wf[kk] = wp[(ct * 3 + kk) * 64 + lane];

  const int ch = ct * 32 + pl;
  const float och = sso[ch];
  const float* xrow = x + (size_t)b * (CIN * HW) + (size_t)(4 * i) * WW;
  const float2* tab2 = (const float2*)stab;
  float* obase = out + ((size_t)(b * COUT + ch)) * 16384 + i * 128;

#pragma unroll
  for (int it = 0; it < 2; ++it) {
    const int jj = it * 64 + pt * 32 + pl;  // load column 0..127

    // ---- A (X) fragments: kk-th needs rows kh=2h,2h+1 of channel ci=kk ----
    const float* xb = xrow + 4 * jj;
    half8 Xf[3];
#pragma unroll
    for (int kk = 0; kk < 3; ++kk) {
      float4 fa = *(const float4*)(xb + (size_t)kk * HW + (2 * h) * WW);
      float4 fb = *(const float4*)(xb + (size_t)kk * HW + (2 * h + 1) * WW);
      Xf[kk] = cvt8_rtz(fa, fb);
    }

    // ---- acc init = per-channel offset (bias folded, table units) ----
    f32x16 acc;
#pragma unroll
    for (int r = 0; r < 16; ++r) acc[r] = och;

#pragma unroll
    for (int kk = 0; kk < 3; ++kk)
      acc = __builtin_amdgcn_mfma_f32_32x32x16_f16(Xf[kk], Wf[kk], acc, 0, 0, 0);

    // ---- epilogue: clamp, gather-lerp, nontemporal float4 stores ----
    // D row (position-in-tile) = (r&3) + 8*(r>>2) + 4*h
    float* ob = obase + it * 64 + pt * 32 + 4 * h;
#pragma unroll
    for (int q = 0; q < 4; ++q) {
      f32x4v res;
#pragma unroll
      for (int m = 0; m < 4; ++m) {
        float u = acc[4 * q + m];
        u = fmaxf(u, 0.0f);
        u = fminf(u, (float)NTAB - 0.0005f);
        const int k = (int)u;
        const float fr = u - (float)k;
        const float2 e = tab2[k];
        res[m] = fmaf(fr, e.y, e.x);
      }
      __builtin_nontemporal_store(res, (f32x4v*)(ob + 8 * q));
    }
  }
}

// ---------------------------------------------------------------------------
// Fallback (exp path) — used only if ws is too small for the table.
// ---------------------------------------------------------------------------
__global__ __launch_bounds__(256) void conv_vq_exp(
    const float* __restrict__ x, const float* __restrict__ w,
    const float* __restrict__ bias, const float* __restrict__ centers,
    const float* __restrict__ sigma_ptr, float* __restrict__ out) {
  const int t = threadIdx.x;
  const int pos = blockIdx.x * 256 + t;
  const int b   = pos >> 14;
  const int rem = pos & 16383;
  const int i   = rem >> 7;
  const int j   = rem & 127;

  const float inv_sigma = 1.0f / sigma_ptr[0];
  float cc[8], tc[8], mc2[8];
#pragma unroll
  for (int k = 0; k < 8; ++k) {
    float c = centers[k];
    cc[k] = c; tc[k] = 2.0f * c; mc2[k] = -c * c;
  }
  const float* xp = x + (size_t)b * (CIN * HW) + (size_t)(4 * i) * WW + 4 * j;
  float p[KF];
#pragma unroll
  for (int ci = 0; ci < CIN; ++ci)
#pragma unroll
    for (int kh = 0; kh < 4; ++kh) {
      float4 v4 = *(const float4*)(xp + (size_t)ci * HW + kh * WW);
      p[(ci * 4 + kh) * 4 + 0] = v4.x;
      p[(ci * 4 + kh) * 4 + 1] = v4.y;
      p[(ci * 4 + kh) * 4 + 2] = v4.z;
      p[(ci * 4 + kh) * 4 + 3] = v4.w;
    }
  float* op = out + (size_t)b * (COUT * HO * WO) + rem;
#pragma unroll 2
  for (int c = 0; c < COUT; ++c) {
    const float4* wr = (const float4*)(w + c * KF);
    float a0 = 0.f, a1 = 0.f, a2 = 0.f, a3 = 0.f;
#pragma unroll
    for (int q = 0; q < 12; ++q) {
      float4 gq = wr[q];
      a0 = fmaf(p[4*q+0], gq.x, a0);
      a1 = fmaf(p[4*q+1], gq.y, a1);
      a2 = fmaf(p[4*q+2], gq.z, a2);
      a3 = fmaf(p[4*q+3], gq.w, a3);
    }
    const float y = fmaf((a0 + a1) + (a2 + a3), inv_sigma, bias[c]);
    float e0 = __expf(fmaf(tc[0], y, mc2[0])), e1 = __expf(fmaf(tc[1], y, mc2[1]));
    float e2 = __expf(fmaf(tc[2], y, mc2[2])), e3 = __expf(fmaf(tc[3], y, mc2[3]));
    float e4 = __expf(fmaf(tc[4], y, mc2[4])), e5 = __expf(fmaf(tc[5], y, mc2[5]));
    float e6 = __expf(fmaf(tc[6], y, mc2[6])), e7 = __expf(fmaf(tc[7], y, mc2[7]));
    float den = ((e0 + e1) + (e2 + e3)) + ((e4 + e5) + (e6 + e7));
    float num = (fmaf(cc[0], e0, cc[1] * e1) + fmaf(cc[2], e2, cc[3] * e3)) +
                (fmaf(cc[4], e4, cc[5] * e5) + fmaf(cc[6], e6, cc[7] * e7));
    op[(size_t)c * (HO * WO)] = __fdividef(num, den);
  }
}

extern "C" void kernel_launch(void* const* d_in, const int* in_sizes, int n_in,
                              void* d_out, int out_size, void* d_ws, size_t ws_size,
                              hipStream_t stream) {
  const float* x       = (const float*)d_in[0];
  const float* w       = (const float*)d_in[1];
  const float* b       = (const float*)d_in[2];
  const float* centers = (const float*)d_in[3];
  float* out = (float*)d_out;
  float* ws  = (float*)d_ws;

  const int use_table = (ws_size >= (size_t)WS_FLOATS * sizeof(float)) ? 1 : 0;

  prep_sigma<<<use_table ? 2 : 1, 256, 0, stream>>>(w, b, centers, ws, use_table);
  if (use_table)
    conv_vq_mfma4<<<(16 * HO * WO) / 128, 256, 0, stream>>>(x, ws, out);
  else
    conv_vq_exp<<<(16 * HO * WO) / 256, 256, 0, stream>>>(x, w, b, centers, ws, out);
}

// Round 11
// 40.733 us; speedup vs baseline: 1.9231x; 1.9231x over previous
//
#include <hip/hip_runtime.h>
#include <stdint.h>

#define CIN 3
#define WW 512
#define HW (512 * 512)
#define COUT 64
#define KF 48          // 3*4*4
#define HO 128
#define WO 128
#define LDA 52

#define NTAB 512
#define YMIN (-12.0f)
#define YMAX (12.0f)
#define INVH ((float)NTAB / (YMAX - YMIN))
// ws layout (floats):
//   [0]=sigma, [1]=a=INVH/sigma, [2..65]=o_c (bias in table units)
//   [128 .. 128+2*NTAB)      = table (f0, df) pairs  (1024 floats)
//   [1152 .. 1152+1536)      = W' f16 fragments (32x32x16 MFMA B-order)
#define WS_TAB_OFF 128
#define WS_WP (WS_TAB_OFF + 2 * NTAB)
#define WS_FLOATS (WS_WP + 1536)

typedef __attribute__((ext_vector_type(16))) float f32x16;
typedef __fp16 half2t __attribute__((ext_vector_type(2)));
typedef __fp16 half8 __attribute__((ext_vector_type(8)));

union H8 { half8 h; half2t h2[4]; __fp16 e[8]; uint32_t u[4]; float f[4]; };

// f32x8 -> f16x8 via packed RTZ converts (1 inst per pair)
__device__ __forceinline__ half8 cvt8_rtz(float4 a, float4 b) {
  H8 r;
  r.h2[0] = __builtin_amdgcn_cvt_pkrtz(a.x, a.y);
  r.h2[1] = __builtin_amdgcn_cvt_pkrtz(a.z, a.w);
  r.h2[2] = __builtin_amdgcn_cvt_pkrtz(b.x, b.y);
  r.h2[3] = __builtin_amdgcn_cvt_pkrtz(b.z, b.w);
  return r.h;
}

__device__ __forceinline__ float vq_eval(float y, const float* __restrict__ c) {
  float d[8], m;
#pragma unroll
  for (int k = 0; k < 8; ++k) { float t = y - c[k]; d[k] = t * t; }
  m = fminf(fminf(fminf(d[0], d[1]), fminf(d[2], d[3])),
            fminf(fminf(d[4], d[5]), fminf(d[6], d[7])));
  float num = 0.f, den = 0.f;
#pragma unroll
  for (int k = 0; k < 8; ++k) {
    float e = __expf(m - d[k]);
    den += e;
    num = fmaf(c[k], e, num);
  }
  return num / den;
}

// ---------------------------------------------------------------------------
// Kernel 1 (2 blocks): block 1 = VQ table + per-channel offsets.
// block 0 = sigma (G=W^T W, 4 squarings, 6 matvecs, Rayleigh), then writes
// W' = W*(INVH/sigma) converted to f16 in 32x32x16 MFMA B-fragment order:
// slot = (ct*3+kk)*64 + lane; ch = ct*32+(lane&31), kbase = kk*16+(lane>>5)*8.
// ---------------------------------------------------------------------------
__global__ __launch_bounds__(256) void prep_sigma(
    const float* __restrict__ w, const float* __restrict__ bias,
    const float* __restrict__ centers, float* __restrict__ ws, int build_tab) {
  const int t = threadIdx.x;

  if (blockIdx.x == 1) {
    float c[8];
#pragma unroll
    for (int k = 0; k < 8; ++k) c[k] = centers[k];
    const float h = (YMAX - YMIN) / (float)NTAB;
#pragma unroll 1
    for (int k = t; k < NTAB; k += 256) {
      float y0 = YMIN + (float)k * h;
      float f0 = vq_eval(y0, c);
      float f1 = vq_eval(y0 + h, c);
      ws[WS_TAB_OFF + 2 * k]     = f0;
      ws[WS_TAB_OFF + 2 * k + 1] = f1 - f0;
    }
    if (t < COUT) ws[2 + t] = (bias[t] - YMIN) * INVH;
    return;
  }

  __shared__ float sW[COUT * KF];
  __shared__ float sG[KF * LDA];
  __shared__ float sA[KF * LDA];
  __shared__ float sB[KF * LDA];
  __shared__ float sv[64];
  __shared__ float sp[256];
  __shared__ float s_a;

  {
    const float4* w4 = (const float4*)w;
    float4* s4 = (float4*)sW;
#pragma unroll
    for (int q = 0; q < 3; ++q) s4[q * 256 + t] = w4[q * 256 + t];
  }
  __syncthreads();

  const int ti = t >> 4, tj = t & 15;
  const int i0 = 3 * ti, j0 = 3 * tj;
  {
    float acc[3][3] = {{0.f}};
#pragma unroll 4
    for (int m = 0; m < COUT; ++m) {
      const float* wr = sW + m * KF;
      float a0 = wr[i0], a1 = wr[i0 + 1], a2 = wr[i0 + 2];
      float b0 = wr[j0], b1 = wr[j0 + 1], b2 = wr[j0 + 2];
      acc[0][0] = fmaf(a0, b0, acc[0][0]);
      acc[0][1] = fmaf(a0, b1, acc[0][1]);
      acc[0][2] = fmaf(a0, b2, acc[0][2]);
      acc[1][0] = fmaf(a1, b0, acc[1][0]);
      acc[1][1] = fmaf(a1, b1, acc[1][1]);
      acc[1][2] = fmaf(a1, b2, acc[1][2]);
      acc[2][0] = fmaf(a2, b0, acc[2][0]);
      acc[2][1] = fmaf(a2, b1, acc[2][1]);
      acc[2][2] = fmaf(a2, b2, acc[2][2]);
    }
#pragma unroll
    for (int ii = 0; ii < 3; ++ii)
#pragma unroll
      for (int jj = 0; jj < 3; ++jj) {
        sG[(i0 + ii) * LDA + j0 + jj] = acc[ii][jj];
        sA[(i0 + ii) * LDA + j0 + jj] = acc[ii][jj];
      }
  }
  __syncthreads();

#pragma unroll 1
  for (int s = 0; s < 4; ++s) {
    const float* src = (s & 1) ? sB : sA;
    float* dst = (s & 1) ? sA : sB;
    float acc[3][3] = {{0.f}};
#pragma unroll
    for (int q = 0; q < 12; ++q) {
      float4 ar0 = *(const float4*)(src + (i0 + 0) * LDA + 4 * q);
      float4 ar1 = *(const float4*)(src + (i0 + 1) * LDA + 4 * q);
      float4 ar2 = *(const float4*)(src + (i0 + 2) * LDA + 4 * q);
      float4 br0 = *(const float4*)(src + (j0 + 0) * LDA + 4 * q);
      float4 br1 = *(const float4*)(src + (j0 + 1) * LDA + 4 * q);
      float4 br2 = *(const float4*)(src + (j0 + 2) * LDA + 4 * q);
#define DOT4(A, B, C) \
      C = fmaf(A.x, B.x, C); C = fmaf(A.y, B.y, C); \
      C = fmaf(A.z, B.z, C); C = fmaf(A.w, B.w, C);
      DOT4(ar0, br0, acc[0][0]); DOT4(ar0, br1, acc[0][1]); DOT4(ar0, br2, acc[0][2]);
      DOT4(ar1, br0, acc[1][0]); DOT4(ar1, br1, acc[1][1]); DOT4(ar1, br2, acc[1][2]);
      DOT4(ar2, br0, acc[2][0]); DOT4(ar2, br1, acc[2][1]); DOT4(ar2, br2, acc[2][2]);
#undef DOT4
    }
    __syncthreads();
#pragma unroll
    for (int ii = 0; ii < 3; ++ii)
#pragma unroll
      for (int jj = 0; jj < 3; ++jj)
        dst[(i0 + ii) * LDA + j0 + jj] = acc[ii][jj];
    __syncthreads();
  }
  const float* M = sA;   // G^16

  if (t < 64) sv[t] = (t < KF) ? 1.0f : 0.f;
  __syncthreads();

#pragma unroll 1
  for (int it = 0; it < 6; ++it) {
    float partial = 0.f;
    if (t < 192) {
      const int row = t >> 2, seg = t & 3;
      const float* mr = M + row * LDA + seg * 12;
      const float4* v4 = (const float4*)sv;
#pragma unroll
      for (int q = 0; q < 3; ++q) {
        float4 m4 = *(const float4*)(mr + 4 * q);
        float4 vv = v4[seg * 3 + q];
        partial = fmaf(m4.x, vv.x, partial);
        partial = fmaf(m4.y, vv.y, partial);
        partial = fmaf(m4.z, vv.z, partial);
        partial = fmaf(m4.w, vv.w, partial);
      }
    }
    sp[t] = partial;
    __syncthreads();
    if (t < 64) {
      float nv = 0.f;
      if (t < KF) nv = (sp[4 * t] + sp[4 * t + 1]) + (sp[4 * t + 2] + sp[4 * t + 3]);
      float ss = nv * nv;
#pragma unroll
      for (int m = 32; m >= 1; m >>= 1) ss += __shfl_xor(ss, m, 64);
      sv[t] = (t < KF) ? nv * rsqrtf(ss) : 0.f;
    }
    __syncthreads();
  }

  {
    float partial = 0.f;
    if (t < 192) {
      const int row = t >> 2, seg = t & 3;
      const float* mr = sG + row * LDA + seg * 12;
      const float4* v4 = (const float4*)sv;
#pragma unroll
      for (int q = 0; q < 3; ++q) {
        float4 m4 = *(const float4*)(mr + 4 * q);
        float4 vv = v4[seg * 3 + q];
        partial = fmaf(m4.x, vv.x, partial);
        partial = fmaf(m4.y, vv.y, partial);
        partial = fmaf(m4.z, vv.z, partial);
        partial = fmaf(m4.w, vv.w, partial);
      }
    }
    sp[t] = partial;
    __syncthreads();
    if (t < 64) {
      float nv = 0.f;
      if (t < KF) nv = (sp[4 * t] + sp[4 * t + 1]) + (sp[4 * t + 2] + sp[4 * t + 3]);
      float vt = sv[t];
      float num = nv * vt;
      float den = vt * vt;
#pragma unroll
      for (int m = 32; m >= 1; m >>= 1) {
        num += __shfl_xor(num, m, 64);
        den += __shfl_xor(den, m, 64);
      }
      if (t == 0) {
        float sg = sqrtf(num / den);
        ws[0] = sg;
        ws[1] = INVH / sg;
        s_a = INVH / sg;
      }
    }
  }
  __syncthreads();

  // ---- W' f16 fragments (B-operand order): 384 slots, strided over 256 thr
  if (build_tab) {
    const float a = s_a;
#pragma unroll 1
    for (int sl = t; sl < 384; sl += 256) {
      const int grp = sl >> 6;       // ct*3 + kk
      const int ct = grp / 3;
      const int kk = grp % 3;
      const int l  = sl & 63;
      const int ch = ct * 32 + (l & 31);
      const int kbase = kk * 16 + (l >> 5) * 8;
      const float* src = w + ch * KF + kbase;
      float4 fa = *(const float4*)(src);
      float4 fb = *(const float4*)(src + 4);
      H8 r;
      r.e[0] = (__fp16)(fa.x * a);
      r.e[1] = (__fp16)(fa.y * a);
      r.e[2] = (__fp16)(fa.z * a);
      r.e[3] = (__fp16)(fa.w * a);
      r.e[4] = (__fp16)(fb.x * a);
      r.e[5] = (__fp16)(fb.y * a);
      r.e[6] = (__fp16)(fb.z * a);
      r.e[7] = (__fp16)(fb.w * a);
      *(float4*)(ws + WS_WP + sl * 4) =
          make_float4(r.f[0], r.f[1], r.f[2], r.f[3]);
    }
  }
}

// ---------------------------------------------------------------------------
// Kernel 2: f16 32x32x16 MFMA conv + table-VQ, operand-swapped, 4-tile loop.
// Block = 4 waves = (2 ct x 2 pt); covers TWO output rows (b, i0..i0+1) =
// 256 positions x 64 ch over NT=4 fully-unrolled tile iterations.
// Grid = 1024 = 4 blocks/CU.  W frags / bias / 4KB table staged once per
// block; unrolled body lets iteration n+1's x-loads issue under iteration
// n's MFMA + epilogue.  Regular (cached) stores — L2 merges them (r9: 65.5MB).
// ---------------------------------------------------------------------------
__global__ __launch_bounds__(256) void conv_vq_mfma5(
    const float* __restrict__ x, const float* __restrict__ params,
    float* __restrict__ out) {
  __shared__ float stab[2 * NTAB];   // 4 KB (f0, df)
  __shared__ float sso[COUT];
  const int t = threadIdx.x;
  {
    const float4* src = (const float4*)(params + WS_TAB_OFF);
    ((float4*)stab)[t] = src[t];     // 2*NTAB*4B / 16B == 256 == blockDim
    if (t < COUT) sso[t] = params[2 + t];
  }
  __syncthreads();

  const int lane = t & 63;
  const int wv   = t >> 6;
  const int ct   = wv & 1;                  // channel tile (32 ch)
  const int pt   = wv >> 1;                 // position subtile (32 pos)
  const int h    = lane >> 5;               // k-half
  const int pl   = lane & 31;               // A-row = position-in-tile

  const int n0   = blockIdx.x * 256;        // two full (b,i) rows
  const int b    = n0 >> 14;
  const int i0   = (n0 & 16383) >> 7;

  // ---- B (W') fragments: loaded once, held across tiles (L2-hot) ----
  const half8* wp = (const half8*)(params + WS_WP);
  half8 Wf[3];
#pragma unroll
  for (int kk = 0; kk < 3; ++kk) Wf[kk] = wp[(ct * 3 + kk) * 64 + lane];

  const int ch = ct * 32 + pl;
  const float och = sso[ch];
  const float* xim = x + (size_t)b * (CIN * HW);
  const float2* tab2 = (const float2*)stab;
  float* och_out = out + ((size_t)(b * COUT + ch)) * 16384;

#pragma unroll
  for (int it = 0; it < 4; ++it) {
    const int base = it * 64 + pt * 32;     // 32-aligned, 0..224
    const int ii   = i0 + (base >> 7);      // output row
    const int jb   = base & 127;            // subtile col base
    const int jj   = jb + pl;               // load column

    // ---- A (X) fragments: kk-th needs rows kh=2h,2h+1 of channel ci=kk ----
    const float* xb = xim + (size_t)(4 * ii) * WW + 4 * jj;
    half8 Xf[3];
#pragma unroll
    for (int kk = 0; kk < 3; ++kk) {
      float4 fa = *(const float4*)(xb + (size_t)kk * HW + (2 * h) * WW);
      float4 fb = *(const float4*)(xb + (size_t)kk * HW + (2 * h + 1) * WW);
      Xf[kk] = cvt8_rtz(fa, fb);
    }

    // ---- acc init = per-channel offset (bias folded, table units) ----
    f32x16 acc;
#pragma unroll
    for (int r = 0; r < 16; ++r) acc[r] = och;

#pragma unroll
    for (int kk = 0; kk < 3; ++kk)
      acc = __builtin_amdgcn_mfma_f32_32x32x16_f16(Xf[kk], Wf[kk], acc, 0, 0, 0);

    // ---- epilogue: clamp, gather-lerp, float4 stores ----
    // D row (position-in-tile) = (r&3) + 8*(r>>2) + 4*h
    float* ob = och_out + ii * 128 + jb + 4 * h;
#pragma unroll
    for (int q = 0; q < 4; ++q) {
      float4 res;
#pragma unroll
      for (int m = 0; m < 4; ++m) {
        float u = acc[4 * q + m];
        u = fmaxf(u, 0.0f);
        u = fminf(u, (float)NTAB - 0.0005f);
        const int k = (int)u;
        const float fr = u - (float)k;
        const float2 e = tab2[k];
        float v = fmaf(fr, e.y, e.x);
        if (m == 0) res.x = v; else if (m == 1) res.y = v;
        else if (m == 2) res.z = v; else res.w = v;
      }
      *(float4*)(ob + 8 * q) = res;
    }
  }
}

// ---------------------------------------------------------------------------
// Fallback (exp path) — used only if ws is too small for the table.
// ---------------------------------------------------------------------------
__global__ __launch_bounds__(256) void conv_vq_exp(
    const float* __restrict__ x, const float* __restrict__ w,
    const float* __restrict__ bias, const float* __restrict__ centers,
    const float* __restrict__ sigma_ptr, float* __restrict__ out) {
  const int t = threadIdx.x;
  const int pos = blockIdx.x * 256 + t;
  const int b   = pos >> 14;
  const int rem = pos & 16383;
  const int i   = rem >> 7;
  const int j   = rem & 127;

  const float inv_sigma = 1.0f / sigma_ptr[0];
  float cc[8], tc[8], mc2[8];
#pragma unroll
  for (int k = 0; k < 8; ++k) {
    float c = centers[k];
    cc[k] = c; tc[k] = 2.0f * c; mc2[k] = -c * c;
  }
  const float* xp = x + (size_t)b * (CIN * HW) + (size_t)(4 * i) * WW + 4 * j;
  float p[KF];
#pragma unroll
  for (int ci = 0; ci < CIN; ++ci)
#pragma unroll
    for (int kh = 0; kh < 4; ++kh) {
      float4 v4 = *(const float4*)(xp + (size_t)ci * HW + kh * WW);
      p[(ci * 4 + kh) * 4 + 0] = v4.x;
      p[(ci * 4 + kh) * 4 + 1] = v4.y;
      p[(ci * 4 + kh) * 4 + 2] = v4.z;
      p[(ci * 4 + kh) * 4 + 3] = v4.w;
    }
  float* op = out + (size_t)b * (COUT * HO * WO) + rem;
#pragma unroll 2
  for (int c = 0; c < COUT; ++c) {
    const float4* wr = (const float4*)(w + c * KF);
    float a0 = 0.f, a1 = 0.f, a2 = 0.f, a3 = 0.f;
#pragma unroll
    for (int q = 0; q < 12; ++q) {
      float4 gq = wr[q];
      a0 = fmaf(p[4*q+0], gq.x, a0);
      a1 = fmaf(p[4*q+1], gq.y, a1);
      a2 = fmaf(p[4*q+2], gq.z, a2);
      a3 = fmaf(p[4*q+3], gq.w, a3);
    }
    const float y = fmaf((a0 + a1) + (a2 + a3), inv_sigma, bias[c]);
    float e0 = __expf(fmaf(tc[0], y, mc2[0])), e1 = __expf(fmaf(tc[1], y, mc2[1]));
    float e2 = __expf(fmaf(tc[2], y, mc2[2])), e3 = __expf(fmaf(tc[3], y, mc2[3]));
    float e4 = __expf(fmaf(tc[4], y, mc2[4])), e5 = __expf(fmaf(tc[5], y, mc2[5]));
    float e6 = __expf(fmaf(tc[6], y, mc2[6])), e7 = __expf(fmaf(tc[7], y, mc2[7]));
    float den = ((e0 + e1) + (e2 + e3)) + ((e4 + e5) + (e6 + e7));
    float num = (fmaf(cc[0], e0, cc[1] * e1) + fmaf(cc[2], e2, cc[3] * e3)) +
                (fmaf(cc[4], e4, cc[5] * e5) + fmaf(cc[6], e6, cc[7] * e7));
    op[(size_t)c * (HO * WO)] = __fdividef(num, den);
  }
}

extern "C" void kernel_launch(void* const* d_in, const int* in_sizes, int n_in,
                              void* d_out, int out_size, void* d_ws, size_t ws_size,
                              hipStream_t stream) {
  const float* x       = (const float*)d_in[0];
  const float* w       = (const float*)d_in[1];
  const float* b       = (const float*)d_in[2];
  const float* centers = (const float*)d_in[3];
  float* out = (float*)d_out;
  float* ws  = (float*)d_ws;

  const int use_table = (ws_size >= (size_t)WS_FLOATS * sizeof(float)) ? 1 : 0;

  prep_sigma<<<use_table ? 2 : 1, 256, 0, stream>>>(w, b, centers, ws, use_table);
  if (use_table)
    conv_vq_mfma5<<<(16 * HO * WO) / 256, 256, 0, stream>>>(x, ws, out);
  else
    conv_vq_exp<<<(16 * HO * WO) / 256, 256, 0, stream>>>(x, w, b, centers, ws, out);
}

// Round 12
// 38.076 us; speedup vs baseline: 2.0573x; 1.0698x over previous
//
#include <hip/hip_runtime.h>
#include <stdint.h>

#define CIN 3
#define WW 512
#define HW (512 * 512)
#define COUT 64
#define KF 48          // 3*4*4
#define HO 128
#define WO 128
#define LDA 52

#define NTAB 512
#define YMIN (-12.0f)
#define YMAX (12.0f)
#define INVH ((float)NTAB / (YMAX - YMIN))
// ws layout (floats):
//   [0]=sigma, [1]=a=INVH/sigma, [2..65]=o_c (bias in table units)
//   [128 .. 128+2*NTAB)      = table (f0, df) pairs  (1024 floats)
//   [1152 .. 1152+1536)      = W' f16 fragments (32x32x16 MFMA order)
#define WS_TAB_OFF 128
#define WS_WP (WS_TAB_OFF + 2 * NTAB)
#define WS_FLOATS (WS_WP + 1536)

typedef __attribute__((ext_vector_type(16))) float f32x16;
typedef __fp16 half2t __attribute__((ext_vector_type(2)));
typedef __fp16 half8 __attribute__((ext_vector_type(8)));

union H8 { half8 h; half2t h2[4]; __fp16 e[8]; uint32_t u[4]; float f[4]; };

// f32x8 -> f16x8 via packed RTZ converts (1 inst per pair)
__device__ __forceinline__ half8 cvt8_rtz(float4 a, float4 b) {
  H8 r;
  r.h2[0] = __builtin_amdgcn_cvt_pkrtz(a.x, a.y);
  r.h2[1] = __builtin_amdgcn_cvt_pkrtz(a.z, a.w);
  r.h2[2] = __builtin_amdgcn_cvt_pkrtz(b.x, b.y);
  r.h2[3] = __builtin_amdgcn_cvt_pkrtz(b.z, b.w);
  return r.h;
}

__device__ __forceinline__ float vq_eval(float y, const float* __restrict__ c) {
  float d[8], m;
#pragma unroll
  for (int k = 0; k < 8; ++k) { float t = y - c[k]; d[k] = t * t; }
  m = fminf(fminf(fminf(d[0], d[1]), fminf(d[2], d[3])),
            fminf(fminf(d[4], d[5]), fminf(d[6], d[7])));
  float num = 0.f, den = 0.f;
#pragma unroll
  for (int k = 0; k < 8; ++k) {
    float e = __expf(m - d[k]);
    den += e;
    num = fmaf(c[k], e, num);
  }
  return num / den;
}

// ---------------------------------------------------------------------------
// Kernel 1 (2 blocks): block 1 = VQ table + per-channel offsets.
// block 0 = sigma (G=W^T W, 4 squarings, 6 matvecs, Rayleigh), then writes
// W' = W*(INVH/sigma) converted to f16 in 32x32x16 MFMA fragment order:
// slot = (ct*3+kk)*64 + lane; ch = ct*32+(lane&31), kbase = kk*16+(lane>>5)*8.
// ---------------------------------------------------------------------------
__global__ __launch_bounds__(256) void prep_sigma(
    const float* __restrict__ w, const float* __restrict__ bias,
    const float* __restrict__ centers, float* __restrict__ ws, int build_tab) {
  const int t = threadIdx.x;

  if (blockIdx.x == 1) {
    float c[8];
#pragma unroll
    for (int k = 0; k < 8; ++k) c[k] = centers[k];
    const float h = (YMAX - YMIN) / (float)NTAB;
#pragma unroll 1
    for (int k = t; k < NTAB; k += 256) {
      float y0 = YMIN + (float)k * h;
      float f0 = vq_eval(y0, c);
      float f1 = vq_eval(y0 + h, c);
      ws[WS_TAB_OFF + 2 * k]     = f0;
      ws[WS_TAB_OFF + 2 * k + 1] = f1 - f0;
    }
    if (t < COUT) ws[2 + t] = (bias[t] - YMIN) * INVH;
    return;
  }

  __shared__ float sW[COUT * KF];
  __shared__ float sG[KF * LDA];
  __shared__ float sA[KF * LDA];
  __shared__ float sB[KF * LDA];
  __shared__ float sv[64];
  __shared__ float sp[256];
  __shared__ float s_a;

  {
    const float4* w4 = (const float4*)w;
    float4* s4 = (float4*)sW;
#pragma unroll
    for (int q = 0; q < 3; ++q) s4[q * 256 + t] = w4[q * 256 + t];
  }
  __syncthreads();

  const int ti = t >> 4, tj = t & 15;
  const int i0 = 3 * ti, j0 = 3 * tj;
  {
    float acc[3][3] = {{0.f}};
#pragma unroll 4
    for (int m = 0; m < COUT; ++m) {
      const float* wr = sW + m * KF;
      float a0 = wr[i0], a1 = wr[i0 + 1], a2 = wr[i0 + 2];
      float b0 = wr[j0], b1 = wr[j0 + 1], b2 = wr[j0 + 2];
      acc[0][0] = fmaf(a0, b0, acc[0][0]);
      acc[0][1] = fmaf(a0, b1, acc[0][1]);
      acc[0][2] = fmaf(a0, b2, acc[0][2]);
      acc[1][0] = fmaf(a1, b0, acc[1][0]);
      acc[1][1] = fmaf(a1, b1, acc[1][1]);
      acc[1][2] = fmaf(a1, b2, acc[1][2]);
      acc[2][0] = fmaf(a2, b0, acc[2][0]);
      acc[2][1] = fmaf(a2, b1, acc[2][1]);
      acc[2][2] = fmaf(a2, b2, acc[2][2]);
    }
#pragma unroll
    for (int ii = 0; ii < 3; ++ii)
#pragma unroll
      for (int jj = 0; jj < 3; ++jj) {
        sG[(i0 + ii) * LDA + j0 + jj] = acc[ii][jj];
        sA[(i0 + ii) * LDA + j0 + jj] = acc[ii][jj];
      }
  }
  __syncthreads();

#pragma unroll 1
  for (int s = 0; s < 4; ++s) {
    const float* src = (s & 1) ? sB : sA;
    float* dst = (s & 1) ? sA : sB;
    float acc[3][3] = {{0.f}};
#pragma unroll
    for (int q = 0; q < 12; ++q) {
      float4 ar0 = *(const float4*)(src + (i0 + 0) * LDA + 4 * q);
      float4 ar1 = *(const float4*)(src + (i0 + 1) * LDA + 4 * q);
      float4 ar2 = *(const float4*)(src + (i0 + 2) * LDA + 4 * q);
      float4 br0 = *(const float4*)(src + (j0 + 0) * LDA + 4 * q);
      float4 br1 = *(const float4*)(src + (j0 + 1) * LDA + 4 * q);
      float4 br2 = *(const float4*)(src + (j0 + 2) * LDA + 4 * q);
#define DOT4(A, B, C) \
      C = fmaf(A.x, B.x, C); C = fmaf(A.y, B.y, C); \
      C = fmaf(A.z, B.z, C); C = fmaf(A.w, B.w, C);
      DOT4(ar0, br0, acc[0][0]); DOT4(ar0, br1, acc[0][1]); DOT4(ar0, br2, acc[0][2]);
      DOT4(ar1, br0, acc[1][0]); DOT4(ar1, br1, acc[1][1]); DOT4(ar1, br2, acc[1][2]);
      DOT4(ar2, br0, acc[2][0]); DOT4(ar2, br1, acc[2][1]); DOT4(ar2, br2, acc[2][2]);
#undef DOT4
    }
    __syncthreads();
#pragma unroll
    for (int ii = 0; ii < 3; ++ii)
#pragma unroll
      for (int jj = 0; jj < 3; ++jj)
        dst[(i0 + ii) * LDA + j0 + jj] = acc[ii][jj];
    __syncthreads();
  }
  const float* M = sA;   // G^16

  if (t < 64) sv[t] = (t < KF) ? 1.0f : 0.f;
  __syncthreads();

#pragma unroll 1
  for (int it = 0; it < 6; ++it) {
    float partial = 0.f;
    if (t < 192) {
      const int row = t >> 2, seg = t & 3;
      const float* mr = M + row * LDA + seg * 12;
      const float4* v4 = (const float4*)sv;
#pragma unroll
      for (int q = 0; q < 3; ++q) {
        float4 m4 = *(const float4*)(mr + 4 * q);
        float4 vv = v4[seg * 3 + q];
        partial = fmaf(m4.x, vv.x, partial);
        partial = fmaf(m4.y, vv.y, partial);
        partial = fmaf(m4.z, vv.z, partial);
        partial = fmaf(m4.w, vv.w, partial);
      }
    }
    sp[t] = partial;
    __syncthreads();
    if (t < 64) {
      float nv = 0.f;
      if (t < KF) nv = (sp[4 * t] + sp[4 * t + 1]) + (sp[4 * t + 2] + sp[4 * t + 3]);
      float ss = nv * nv;
#pragma unroll
      for (int m = 32; m >= 1; m >>= 1) ss += __shfl_xor(ss, m, 64);
      sv[t] = (t < KF) ? nv * rsqrtf(ss) : 0.f;
    }
    __syncthreads();
  }

  {
    float partial = 0.f;
    if (t < 192) {
      const int row = t >> 2, seg = t & 3;
      const float* mr = sG + row * LDA + seg * 12;
      const float4* v4 = (const float4*)sv;
#pragma unroll
      for (int q = 0; q < 3; ++q) {
        float4 m4 = *(const float4*)(mr + 4 * q);
        float4 vv = v4[seg * 3 + q];
        partial = fmaf(m4.x, vv.x, partial);
        partial = fmaf(m4.y, vv.y, partial);
        partial = fmaf(m4.z, vv.z, partial);
        partial = fmaf(m4.w, vv.w, partial);
      }
    }
    sp[t] = partial;
    __syncthreads();
    if (t < 64) {
      float nv = 0.f;
      if (t < KF) nv = (sp[4 * t] + sp[4 * t + 1]) + (sp[4 * t + 2] + sp[4 * t + 3]);
      float vt = sv[t];
      float num = nv * vt;
      float den = vt * vt;
#pragma unroll
      for (int m = 32; m >= 1; m >>= 1) {
        num += __shfl_xor(num, m, 64);
        den += __shfl_xor(den, m, 64);
      }
      if (t == 0) {
        float sg = sqrtf(num / den);
        ws[0] = sg;
        ws[1] = INVH / sg;
        s_a = INVH / sg;
      }
    }
  }
  __syncthreads();

  // ---- W' f16 fragments: 384 slots, strided over 256 threads ----
  if (build_tab) {
    const float a = s_a;
#pragma unroll 1
    for (int sl = t; sl < 384; sl += 256) {
      const int grp = sl >> 6;       // ct*3 + kk
      const int ct = grp / 3;
      const int kk = grp % 3;
      const int l  = sl & 63;
      const int ch = ct * 32 + (l & 31);
      const int kbase = kk * 16 + (l >> 5) * 8;
      const float* src = w + ch * KF + kbase;
      float4 fa = *(const float4*)(src);
      float4 fb = *(const float4*)(src + 4);
      H8 r;
      r.e[0] = (__fp16)(fa.x * a);
      r.e[1] = (__fp16)(fa.y * a);
      r.e[2] = (__fp16)(fa.z * a);
      r.e[3] = (__fp16)(fa.w * a);
      r.e[4] = (__fp16)(fb.x * a);
      r.e[5] = (__fp16)(fb.y * a);
      r.e[6] = (__fp16)(fb.z * a);
      r.e[7] = (__fp16)(fb.w * a);
      *(float4*)(ws + WS_WP + sl * 4) =
          make_float4(r.f[0], r.f[1], r.f[2], r.f[3]);
    }
  }
}

// ---------------------------------------------------------------------------
// Kernel 2: f16 32x32x16 MFMA conv + table-VQ, A=W' (r6 orientation:
// contiguous per-channel-row stores), explicit register double-buffer over
// NT=2 tiles.  Block = 4 waves (2 ct x 2 pt) covering one full output row
// (b,i): 128 pos x 64 ch.  Grid = 2048.  Tile-1's 6 float4 x-loads issue
// into nxt[] BEFORE tile-0's cvt/MFMA/epilogue -> loads stay in flight
// under compute (counted vmcnt).
// ---------------------------------------------------------------------------
__global__ __launch_bounds__(256) void conv_vq_mfma6(
    const float* __restrict__ x, const float* __restrict__ params,
    float* __restrict__ out) {
  __shared__ float stab[2 * NTAB];   // 4 KB (f0, df)
  __shared__ float sso[COUT];
  const int t = threadIdx.x;
  {
    const float4* src = (const float4*)(params + WS_TAB_OFF);
    ((float4*)stab)[t] = src[t];     // 2*NTAB*4B/16B == 256 == blockDim
    if (t < COUT) sso[t] = params[2 + t];
  }
  __syncthreads();

  const int lane = t & 63;
  const int wv   = t >> 6;
  const int ct   = wv & 1;                  // channel tile (32 ch)
  const int pt   = wv >> 1;                 // position subtile (32 pos)
  const int h    = lane >> 5;               // k-half
  const int pl   = lane & 31;               // B-col = position-in-tile

  const int n0   = blockIdx.x * 128;        // one full (b,i) output row
  const int b    = n0 >> 14;
  const int i    = (n0 & 16383) >> 7;

  // ---- A (W') fragments: lane&31 = ch row, k = (lane>>5)*8 + e ----
  const half8* wp = (const half8*)(params + WS_WP);
  half8 Wf[3];
#pragma unroll
  for (int kk = 0; kk < 3; ++kk) Wf[kk] = wp[(ct * 3 + kk) * 64 + lane];

  const float* xrow = x + (size_t)b * (CIN * HW) + (size_t)(4 * i) * WW;
  const float2* tab2 = (const float2*)stab;
  // store base: channel rows ct*32+4h+..., position col added per tile
  float* ob0 = out + ((size_t)(b * COUT + ct * 32 + 4 * h)) * 16384 + i * 128;
  const float* sob = sso + ct * 32 + 4 * h;

  // ---- prefetch tile 0 ----
  float4 cur[6];
  {
    const float* xb = xrow + 4 * (pt * 32 + pl);
#pragma unroll
    for (int kk = 0; kk < 3; ++kk) {
      cur[2 * kk + 0] = *(const float4*)(xb + (size_t)kk * HW + (2 * h) * WW);
      cur[2 * kk + 1] = *(const float4*)(xb + (size_t)kk * HW + (2 * h + 1) * WW);
    }
  }

#pragma unroll
  for (int it = 0; it < 2; ++it) {
    // ---- issue next tile's loads FIRST (stay in flight under compute) ----
    float4 nxt[6];
    if (it == 0) {
      const float* xb = xrow + 4 * (64 + pt * 32 + pl);
#pragma unroll
      for (int kk = 0; kk < 3; ++kk) {
        nxt[2 * kk + 0] = *(const float4*)(xb + (size_t)kk * HW + (2 * h) * WW);
        nxt[2 * kk + 1] = *(const float4*)(xb + (size_t)kk * HW + (2 * h + 1) * WW);
      }
    }

    // ---- convert current tile, MFMA ----
    half8 Xf[3];
#pragma unroll
    for (int kk = 0; kk < 3; ++kk) Xf[kk] = cvt8_rtz(cur[2 * kk], cur[2 * kk + 1]);

    f32x16 acc;
#pragma unroll
    for (int r = 0; r < 16; ++r) acc[r] = sob[(r & 3) + 8 * (r >> 2)];

#pragma unroll
    for (int kk = 0; kk < 3; ++kk)
      acc = __builtin_amdgcn_mfma_f32_32x32x16_f16(Wf[kk], Xf[kk], acc, 0, 0, 0);

    // ---- epilogue: clamp, gather-lerp, contiguous dword stores ----
    // D col(pos) = lane&31, row(ch-in-tile) = (r&3)+8*(r>>2)+4h
    float* ob = ob0 + it * 64 + pt * 32 + pl;
#pragma unroll
    for (int r = 0; r < 16; ++r) {
      float u = acc[r];
      u = fmaxf(u, 0.0f);
      u = fminf(u, (float)NTAB - 0.0005f);
      const int k = (int)u;
      const float fr = u - (float)k;
      const float2 e = tab2[k];
      ob[(size_t)((r & 3) + 8 * (r >> 2)) * 16384] = fmaf(fr, e.y, e.x);
    }

    // ---- rotate buffers ----
#pragma unroll
    for (int q = 0; q < 6; ++q) cur[q] = nxt[q];
  }
}

// ---------------------------------------------------------------------------
// Fallback (exp path) — used only if ws is too small for the table.
// ---------------------------------------------------------------------------
__global__ __launch_bounds__(256) void conv_vq_exp(
    const float* __restrict__ x, const float* __restrict__ w,
    const float* __restrict__ bias, const float* __restrict__ centers,
    const float* __restrict__ sigma_ptr, float* __restrict__ out) {
  const int t = threadIdx.x;
  const int pos = blockIdx.x * 256 + t;
  const int b   = pos >> 14;
  const int rem = pos & 16383;
  const int i   = rem >> 7;
  const int j   = rem & 127;

  const float inv_sigma = 1.0f / sigma_ptr[0];
  float cc[8], tc[8], mc2[8];
#pragma unroll
  for (int k = 0; k < 8; ++k) {
    float c = centers[k];
    cc[k] = c; tc[k] = 2.0f * c; mc2[k] = -c * c;
  }
  const float* xp = x + (size_t)b * (CIN * HW) + (size_t)(4 * i) * WW + 4 * j;
  float p[KF];
#pragma unroll
  for (int ci = 0; ci < CIN; ++ci)
#pragma unroll
    for (int kh = 0; kh < 4; ++kh) {
      float4 v4 = *(const float4*)(xp + (size_t)ci * HW + kh * WW);
      p[(ci * 4 + kh) * 4 + 0] = v4.x;
      p[(ci * 4 + kh) * 4 + 1] = v4.y;
      p[(ci * 4 + kh) * 4 + 2] = v4.z;
      p[(ci * 4 + kh) * 4 + 3] = v4.w;
    }
  float* op = out + (size_t)b * (COUT * HO * WO) + rem;
#pragma unroll 2
  for (int c = 0; c < COUT; ++c) {
    const float4* wr = (const float4*)(w + c * KF);
    float a0 = 0.f, a1 = 0.f, a2 = 0.f, a3 = 0.f;
#pragma unroll
    for (int q = 0; q < 12; ++q) {
      float4 gq = wr[q];
      a0 = fmaf(p[4*q+0], gq.x, a0);
      a1 = fmaf(p[4*q+1], gq.y, a1);
      a2 = fmaf(p[4*q+2], gq.z, a2);
      a3 = fmaf(p[4*q+3], gq.w, a3);
    }
    const float y = fmaf((a0 + a1) + (a2 + a3), inv_sigma, bias[c]);
    float e0 = __expf(fmaf(tc[0], y, mc2[0])), e1 = __expf(fmaf(tc[1], y, mc2[1]));
    float e2 = __expf(fmaf(tc[2], y, mc2[2])), e3 = __expf(fmaf(tc[3], y, mc2[3]));
    float e4 = __expf(fmaf(tc[4], y, mc2[4])), e5 = __expf(fmaf(tc[5], y, mc2[5]));
    float e6 = __expf(fmaf(tc[6], y, mc2[6])), e7 = __expf(fmaf(tc[7], y, mc2[7]));
    float den = ((e0 + e1) + (e2 + e3)) + ((e4 + e5) + (e6 + e7));
    float num = (fmaf(cc[0], e0, cc[1] * e1) + fmaf(cc[2], e2, cc[3] * e3)) +
                (fmaf(cc[4], e4, cc[5] * e5) + fmaf(cc[6], e6, cc[7] * e7));
    op[(size_t)c * (HO * WO)] = __fdividef(num, den);
  }
}

extern "C" void kernel_launch(void* const* d_in, const int* in_sizes, int n_in,
                              void* d_out, int out_size, void* d_ws, size_t ws_size,
                              hipStream_t stream) {
  const float* x       = (const float*)d_in[0];
  const float* w       = (const float*)d_in[1];
  const float* b       = (const float*)d_in[2];
  const float* centers = (const float*)d_in[3];
  float* out = (float*)d_out;
  float* ws  = (float*)d_ws;

  const int use_table = (ws_size >= (size_t)WS_FLOATS * sizeof(float)) ? 1 : 0;

  prep_sigma<<<use_table ? 2 : 1, 256, 0, stream>>>(w, b, centers, ws, use_table);
  if (use_table)
    conv_vq_mfma6<<<(16 * HO * WO) / 128, 256, 0, stream>>>(x, ws, out);
  else
    conv_vq_exp<<<(16 * HO * WO) / 256, 256, 0, stream>>>(x, w, b, centers, ws, out);
}